// Round 3
// baseline (458.893 us; speedup 1.0000x reference)
//
#include <hip/hip_runtime.h>

// 9x9 local-max peak detection (threshold 0.5) on 8192x8192 fp32.
//
// conf[r][c] = (M > 0.5 && M == raw[r][c]) ? M : 0, where M = 9x9 raw max
// (threshold commutes with max; 0-pad == -inf pad given the >0.5 gate).
//
// Streaming, no LDS/barriers: wave owns a 256-col band (lane = 4 cols),
// rolls 64 output rows. Per row: 3 overlapping float4 loads (branchless,
// clamped addresses + cndmask-zero), horizontal 9-max (shared-prefix),
// 9-deep hm register ring, vertical 9-max, center re-load for the peak
// compare (drops the 36-VGPR ce ring), non-temporal float4 store.
// Unroll-by-9 keeps ring indices static; all loads unconditional ->
// compiler can hoist/pipeline deeply.

#define W 8192
#define H 8192
#define THRESH 0.5f

typedef float v4f __attribute__((ext_vector_type(4)));

__global__ __launch_bounds__(256, 4) void peak_stream(const float* __restrict__ in,
                                                      float* __restrict__ out) {
    const int lane = threadIdx.x;                         // 0..63
    const int col0 = blockIdx.x * 256 + lane * 4;         // lane's 4 output cols
    const int r0   = (blockIdx.y * 4 + threadIdx.y) * 64; // strip's first output row

    // Per-lane constant column handling (only block-edge lanes are OOB).
    const int  cl  = col0 - 4;
    const int  cr  = col0 + 4;
    const bool lok = (cl >= 0);
    const bool rok = (cr + 3 < W);
    const int  clc = lok ? cl : 0;        // safe aligned fallback addr
    const int  crc = rok ? cr : (W - 8);

    v4f hm[9];  // ring: horizontal 9-max of input rows rin-8..rin

    const v4f z = {0.f, 0.f, 0.f, 0.f};

    auto dorow = [&](int rin, int k, bool emit) {
        // Branchless row clamp: loads always execute at a safe address,
        // results zeroed when the true row is out of range (wave-uniform).
        const int  rc     = min(max(rin, 0), H - 1);
        const bool rvalid = (rc == rin);
        const float* rowp = in + (size_t)rc * W;
        v4f l = *(const v4f*)(rowp + clc);
        v4f v = *(const v4f*)(rowp + col0);
        v4f r = *(const v4f*)(rowp + crc);
        l = (rvalid && lok) ? l : z;
        v = rvalid ? v : z;
        r = (rvalid && rok) ? r : z;
        // L = [l0..l3 v0..v3 r0..r3] = cols col0-4 .. col0+7.
        const float common = fmaxf(fmaxf(fmaxf(l.w, v.x), fmaxf(v.y, v.z)),
                                   fmaxf(v.w, r.x));       // max L[3..8]
        const float m12  = fmaxf(l.y, l.z);
        const float m910 = fmaxf(r.y, r.z);
        v4f o;
        o.x = fmaxf(common, fmaxf(l.x, m12));
        o.y = fmaxf(common, fmaxf(m12, r.y));
        o.z = fmaxf(common, fmaxf(l.z, m910));
        o.w = fmaxf(common, fmaxf(m910, r.w));
        hm[k] = o;
        if (emit) {
            v4f m = hm[0];
#pragma unroll
            for (int j = 1; j < 9; ++j) {
                m.x = fmaxf(m.x, hm[j].x);
                m.y = fmaxf(m.y, hm[j].y);
                m.z = fmaxf(m.z, hm[j].z);
                m.w = fmaxf(m.w, hm[j].w);
            }
            const int rout = rin - 4;                      // always in [0, H)
            const v4f c4 = *(const v4f*)(in + (size_t)rout * W + col0);
            v4f ov;
            ov.x = (m.x > THRESH && m.x == c4.x) ? m.x : 0.f;
            ov.y = (m.y > THRESH && m.y == c4.y) ? m.y : 0.f;
            ov.z = (m.z > THRESH && m.z == c4.z) ? m.z : 0.f;
            ov.w = (m.w > THRESH && m.w == c4.w) ? m.w : 0.f;
            __builtin_nontemporal_store(ov, (v4f*)(out + (size_t)rout * W + col0));
        }
    };

    // Prologue: fill ring with input rows r0-4 .. r0+4; slot 8 emits row r0.
#pragma unroll
    for (int t = 0; t < 9; ++t) {
        dorow(r0 - 4 + t, t, t >= 8);
    }
    // Main: 7 chunks of 9 rows; chunk-aligned so ring slot == k (static).
    for (int tc = 9; tc < 72; tc += 9) {
#pragma unroll
        for (int k = 0; k < 9; ++k) {
            dorow(r0 - 4 + tc + k, k, true);
        }
    }
}

extern "C" void kernel_launch(void* const* d_in, const int* in_sizes, int n_in,
                              void* d_out, int out_size, void* d_ws, size_t ws_size,
                              hipStream_t stream) {
    const float* in = (const float*)d_in[0];
    float* out = (float*)d_out;
    dim3 grid(W / 256, H / 256);   // 32 x 32 blocks
    dim3 block(64, 4, 1);          // 4 waves/block, wave ty = strip 4*by+ty
    peak_stream<<<grid, block, 0, stream>>>(in, out);
}

// Round 4
// 441.463 us; speedup vs baseline: 1.0395x; 1.0395x over previous
//
#include <hip/hip_runtime.h>

// 9x9 local-max peak detection (threshold 0.5) on 8192x8192 fp32.
//
// conf[r][c] = (M > 0.5 && M == raw[r][c]) ? M : 0, where M = 9x9 raw max
// (threshold commutes with max; 0-pad == -inf pad given the >0.5 gate).
//
// R4: MLP-batched streaming. Wave owns a 256-col band (lane = 4 cols) and
// rolls 64 output rows in chunks of 9. Per chunk: phase A issues all 27
// row loads back-to-back (27 KB/wave in flight); phase B/C does horizontal
// 9-max + ring vertical 9-max + peak predicate + store, slot-static.
// Boundary handling is pure clamp-duplication: clamped rows/cols reload a
// value that is inside the true window, so max is unchanged and there are
// ZERO boundary selects in the inner loop.

#define W 8192
#define H 8192
#define THRESH 0.5f

typedef float v4f __attribute__((ext_vector_type(4)));

__global__ __launch_bounds__(256, 2) void peak_stream(const float* __restrict__ in,
                                                      float* __restrict__ out) {
    const int lane = threadIdx.x;                         // 0..63
    const int col0 = blockIdx.x * 256 + lane * 4;         // lane's 4 output cols
    const int r0   = (blockIdx.y * 4 + threadIdx.y) * 64; // strip's first output row

    // Clamp-duplication halo columns: duplicated values stay inside the
    // 9-wide window of every affected output -> no zero-selects needed.
    const int clc = max(col0 - 4, 0);
    const int crc = min(col0 + 4, W - 4);

    v4f VL[9], VV[9], VR[9];  // batched loads: 27 in flight per chunk
    v4f hm[9];                // horizontal-max ring; slot = (row - (r0-4)) mod 9
    v4f pv[4];                // prev chunk's VV[5..8] = centers for k=0..3

    auto loadrow = [&](int rin, int k) {
        const int rc = min(max(rin, 0), H - 1);  // row clamp-duplication
        const float* rowp = in + (size_t)rc * W;
        VL[k] = *(const v4f*)(rowp + clc);
        VV[k] = *(const v4f*)(rowp + col0);
        VR[k] = *(const v4f*)(rowp + crc);
    };

    auto hrow = [&](int k) {
        const v4f l = VL[k], v = VV[k], r = VR[k];
        // L = [l0..l3 v0..v3 r0..r3] = cols col0-4 .. col0+7; o_j = max L[j..j+8]
        const float common = fmaxf(fmaxf(fmaxf(l.w, v.x), fmaxf(v.y, v.z)),
                                   fmaxf(v.w, r.x));       // max L[3..8]
        const float m12  = fmaxf(l.y, l.z);
        const float m910 = fmaxf(r.y, r.z);
        v4f o;
        o.x = fmaxf(common, fmaxf(l.x, m12));
        o.y = fmaxf(common, fmaxf(m12, r.y));
        o.z = fmaxf(common, fmaxf(l.z, m910));
        o.w = fmaxf(common, fmaxf(m910, r.w));
        hm[k] = o;
    };

    auto emitrow = [&](int rout, v4f c) {
        v4f m = hm[0];
#pragma unroll
        for (int j = 1; j < 9; ++j) {
            m.x = fmaxf(m.x, hm[j].x);
            m.y = fmaxf(m.y, hm[j].y);
            m.z = fmaxf(m.z, hm[j].z);
            m.w = fmaxf(m.w, hm[j].w);
        }
        v4f ov;
        ov.x = (m.x > THRESH && m.x == c.x) ? m.x : 0.f;
        ov.y = (m.y > THRESH && m.y == c.y) ? m.y : 0.f;
        ov.z = (m.z > THRESH && m.z == c.z) ? m.z : 0.f;
        ov.w = (m.w > THRESH && m.w == c.w) ? m.w : 0.f;
        *(v4f*)(out + (size_t)rout * W + col0) = ov;
    };

    // Prologue chunk: input rows r0-4 .. r0+4 -> slots 0..8; emits row r0.
#pragma unroll
    for (int k = 0; k < 9; ++k) loadrow(r0 - 4 + k, k);
#pragma unroll
    for (int k = 0; k < 9; ++k) hrow(k);
    emitrow(r0, VV[4]);
#pragma unroll
    for (int j = 0; j < 4; ++j) pv[j] = VV[5 + j];

    // Main: 7 chunks of 9 rows; 9 | chunk so ring slot == k (static).
    for (int c = 1; c < 8; ++c) {
        const int q = r0 - 4 + 9 * c;
#pragma unroll
        for (int k = 0; k < 9; ++k) loadrow(q + k, k);   // 27 loads in flight
#pragma unroll
        for (int k = 0; k < 9; ++k) {
            hrow(k);                                      // row q+k -> slot k
            // emit row q+k-4; window rows q+k-8..q+k == ring slots 0..8
            emitrow(q + k - 4, (k < 4) ? pv[k] : VV[k - 4]);
        }
#pragma unroll
        for (int j = 0; j < 4; ++j) pv[j] = VV[5 + j];
    }
}

extern "C" void kernel_launch(void* const* d_in, const int* in_sizes, int n_in,
                              void* d_out, int out_size, void* d_ws, size_t ws_size,
                              hipStream_t stream) {
    const float* in = (const float*)d_in[0];
    float* out = (float*)d_out;
    dim3 grid(W / 256, H / 256);   // 32 x 32 blocks
    dim3 block(64, 4, 1);          // 4 waves/block; wave ty owns strip 4*by+ty
    peak_stream<<<grid, block, 0, stream>>>(in, out);
}